// Round 1
// 190.495 us; speedup vs baseline: 1.1258x; 1.1258x over previous
//
#include <hip/hip_runtime.h>

#define NPTS  64
#define NANG  2016          // 64*63/2
#define NCOLS 300000
#define NC4   (NCOLS / 4)   // 75000 float4 columns

typedef float v4 __attribute__((ext_vector_type(4)));

// ---------------------------------------------------------------------------
// Kernel 1: build A^T (mus folded) into d_ws as AT[k*64 + row] = mus[row]*R[row][k].
// One wave; lane = column of R. Shift-register S[i] = row (t+i) of this lane's
// column; each rotation writes S[i-1] (shift is free) so the outer t-loop stays
// rolled, and all S indices are compile-time (registers).
//
// R5 theory: R4 measured 70.9us ~= 170k cyc ~= 1070 cyc per 16-rotation chunk
// = 8 x ds_read latency (~120cyc, single wave). The LDS cs_tab round-trip was
// the bottleneck: at VGPR=140 the "prefetch" buffer could not stay live, so the
// 8 ds_read_b128/chunk latency-serialized. (c,s) are wave-uniform scalars, so
// LDS staging is structurally unnecessary:
//   - per group t, lane l loads angle (t, t+l+1) with ONE coalesced global
//     load, software-pipelined 2 groups ahead (covers ~200cyc L2 latency);
//   - one sincosf per lane per group, pipelined 1 group ahead;
//   - the rotation loop broadcasts lane (i-1)'s (c,s) via v_readlane_b32
//     (register-file broadcast, imm lane index, zero memory latency; SGPR
//     result feeds one operand of each v_mul/v_fma, which is legal).
// Groups padded to LEN in {64,48,32,16} with identity rotations (c=1,s=0):
// identity performs a pure shift, junk only moves into already-dead S slots
// (S extended to 65 entries so the i=64 pad access is in-bounds).
// Rotation arithmetic (fmaf forms, sincosf, order) is unchanged vs the passing
// kernel, so absmax should be identical.
// ---------------------------------------------------------------------------

__device__ __forceinline__ float rl(float x, int lane) {
    return __uint_as_float(__builtin_amdgcn_readlane(__float_as_uint(x), lane));
}

// angle for rotation (t, t+lane+1); clamped in-bounds for pipeline overrun
__device__ __forceinline__ float load_ang(const float* __restrict__ angles,
                                          int t, int lane) {
    int base = 63 * t - (t * (t - 1)) / 2;   // t <= 64 -> no overflow
    int idx  = base + lane;
    idx = idx < NANG ? idx : NANG - 1;
    return angles[idx];
}

// (c,s) for group t from the prefetched angle; identity for padded slots
__device__ __forceinline__ void make_cs(float a, int t, int lane,
                                        float& c, float& s) {
    const int real = 63 - t;                 // # real rotations in group t
    const float ang = (lane < real) ? a : 0.0f;   // sincosf(0) -> (c,s)=(1,0)
    sincosf(ang, &s, &c);
}

template<int LEN>  // multiple of 16, LEN >= 63 - t0 at phase start
__device__ __forceinline__ void run_groups(float (&S)[NPTS + 1], int t0, int t1,
                                           const float* __restrict__ angles,
                                           float* __restrict__ AT_out, int lane,
                                           float musv,
                                           float& c0, float& s0, float& a1)
{
    for (int t = t0; t < t1; ++t) {
        // pipeline: issue load for group t+2; sincos for group t+1 (indep of
        // the rotation chain -> compiler interleaves it under the readlane/fma
        // stream); rotate group t with (c0,s0).
        const float a2 = load_ang(angles, t + 2, lane);
        float c1, s1;
        make_cs(a1, t + 1, lane, c1, s1);

        float rt = S[0];
        #pragma unroll
        for (int i = 1; i <= LEN; ++i) {              // compile-time i
            const float c  = rl(c0, i - 1);           // v_readlane, imm lane
            const float s  = rl(s0, i - 1);
            const float rb = S[i];
            S[i - 1] = fmaf(s, rt, c * rb);           // new row (t+i), pre-shifted
            rt       = fmaf(c, rt, -s * rb);          // serial chain
        }
        AT_out[lane * NPTS + t] = rl(musv, t) * rt;   // row t finished

        c0 = c1; s0 = s1; a1 = a2;
    }
}

__global__ __launch_bounds__(64, 1) void ortho_build_R(
    const float* __restrict__ angles, const float* __restrict__ mus,
    float* __restrict__ AT_out)
{
    const int lane = threadIdx.x;
    const float musv = mus[lane];                     // broadcast later via readlane

    float S[NPTS + 1];
    #pragma unroll
    for (int i = 0; i <= NPTS; ++i)
        S[i] = (i == lane) ? 1.0f : 0.0f;

    // pipeline prologue: (c0,s0) for group 0, angle for group 1 in flight
    const float a0 = load_ang(angles, 0, lane);
    float c0, s0;
    make_cs(a0, 0, lane, c0, s0);
    float a1 = load_ang(angles, 1, lane);

    // phase LEN must be >= 63 - t at phase start (and a multiple of 16)
    run_groups<64>(S,  0, 16, angles, AT_out, lane, musv, c0, s0, a1);
    run_groups<48>(S, 16, 32, angles, AT_out, lane, musv, c0, s0, a1);
    run_groups<32>(S, 32, 48, angles, AT_out, lane, musv, c0, s0, a1);
    run_groups<16>(S, 48, 63, angles, AT_out, lane, musv, c0, s0, a1);

    AT_out[lane * NPTS + 63] = rl(musv, 63) * S[0];   // last row
}

// ---------------------------------------------------------------------------
// Kernel 2: Y = A @ X (unchanged — byte-identical to keep the build_R delta
// attribution clean). Thread tile = 16 rows x 4 cols; A reads wave-uniform-
// address global loads; X coalesced float4, double-buffered.
// ---------------------------------------------------------------------------
__device__ __forceinline__ void step16(v4 (&acc)[16], const float* __restrict__ Ak,
                                       const v4 xv)
{
    #pragma unroll
    for (int q = 0; q < 4; ++q) {
        const v4 a = *(const v4*)(Ak + 4 * q);
        acc[4 * q + 0] += xv * a.x;
        acc[4 * q + 1] += xv * a.y;
        acc[4 * q + 2] += xv * a.z;
        acc[4 * q + 3] += xv * a.w;
    }
}

__global__ __launch_bounds__(256) void ortho_apply(
    const float* __restrict__ X, const float* __restrict__ AT,
    float* __restrict__ Y)
{
    const int tc = threadIdx.x & 63;
    const int wv = threadIdx.x >> 6;
    const int tr = __builtin_amdgcn_readfirstlane(wv);   // wave-uniform 0..3
    const int r0 = tr * 16;

    const int j4 = blockIdx.x * 64 + tc;                 // float4 column index
    if (j4 >= NC4) return;

    const v4* xp = (const v4*)X + j4;                    // row stride NC4

    v4 acc[16];
    #pragma unroll
    for (int i = 0; i < 16; ++i) acc[i] = (v4)0.0f;

    v4 xa[4], xb[4];
    #pragma unroll
    for (int q = 0; q < 4; ++q) xa[q] = xp[q * NC4];

    for (int k0 = 0; k0 < NPTS; k0 += 8) {
        #pragma unroll
        for (int q = 0; q < 4; ++q) xb[q] = xp[(k0 + 4 + q) * NC4];
        #pragma unroll
        for (int q = 0; q < 4; ++q) step16(acc, AT + (k0 + q) * NPTS + r0, xa[q]);
        #pragma unroll
        for (int q = 0; q < 4; ++q) xa[q] = xp[((k0 + 8 + q) & 63) * NC4]; // wraps last iter (harmless)
        #pragma unroll
        for (int q = 0; q < 4; ++q) step16(acc, AT + (k0 + 4 + q) * NPTS + r0, xb[q]);
    }

    #pragma unroll
    for (int i = 0; i < 16; ++i) {
        v4* yp = (v4*)(Y + (size_t)(r0 + i) * NCOLS) + j4;
        __builtin_nontemporal_store(acc[i], yp);
    }
}

// ---------------------------------------------------------------------------
extern "C" void kernel_launch(void* const* d_in, const int* in_sizes, int n_in,
                              void* d_out, int out_size, void* d_ws, size_t ws_size,
                              hipStream_t stream) {
    const float* X      = (const float*)d_in[0];   // 64 x 300000
    const float* angles = (const float*)d_in[1];   // 2016
    const float* mus    = (const float*)d_in[2];   // 64
    float* Y  = (float*)d_out;                     // 64 x 300000
    float* AT = (float*)d_ws;                      // 64 x 64 scratch

    ortho_build_R<<<1, 64, 0, stream>>>(angles, mus, AT);

    const int nblk = (NC4 + 63) / 64;              // 1172
    ortho_apply<<<nblk, 256, 0, stream>>>(X, AT, Y);
}